// Round 13
// baseline (356.692 us; speedup 1.0000x reference)
//
#include <hip/hip_runtime.h>
#include <math.h>

#define N_NODES 50000
#define N_EDGES 500000
#define NLAYERS 6
#define NEG_SLOPE 0.2f
#define LN_EPS 1e-5f
#define SCAN_B 1024
#define NSCAN_BLOCKS ((N_NODES + SCAN_B - 1) / SCAN_B)  // 49
#define LOG2E 1.4426950408889634f

typedef __attribute__((ext_vector_type(8))) short short8;
typedef __attribute__((ext_vector_type(4))) float f32x4;

__device__ __forceinline__ float wave_sum64(float v) {
#pragma unroll
    for (int m = 32; m >= 1; m >>= 1) v += __shfl_xor(v, m, 64);
    return v;
}

// sum over each 16-lane row via DPP row-rotates (VALU pipe, no DS ops)
__device__ __forceinline__ float dpp_rowsum16(float v) {
    int x = __float_as_int(v);
    int y = __builtin_amdgcn_update_dpp(x, x, 0x121, 0xf, 0xf, false);  // ror:1
    v += __int_as_float(y);
    x = __float_as_int(v);
    y = __builtin_amdgcn_update_dpp(x, x, 0x122, 0xf, 0xf, false);  // ror:2
    v += __int_as_float(y);
    x = __float_as_int(v);
    y = __builtin_amdgcn_update_dpp(x, x, 0x124, 0xf, 0xf, false);  // ror:4
    v += __int_as_float(y);
    x = __float_as_int(v);
    y = __builtin_amdgcn_update_dpp(x, x, 0x128, 0xf, 0xf, false);  // ror:8
    v += __int_as_float(y);
    return v;
}

__device__ __forceinline__ float wave_sum64_fast(float v) {
    v = dpp_rowsum16(v);
    v += __shfl_xor(v, 16, 64);
    v += __shfl_xor(v, 32, 64);
    return v;
}

__device__ __forceinline__ int wave_incl_scan(int v, int lane) {
#pragma unroll
    for (int offs = 1; offs < 64; offs <<= 1) {
        int t = __shfl_up(v, offs, 64);
        if (lane >= offs) v += t;
    }
    return v;
}

__device__ __forceinline__ unsigned bf16_rne(float v) {
    unsigned u = __float_as_uint(v);
    return (u + 0x7fffu + ((u >> 16) & 1u)) >> 16;
}

__device__ __forceinline__ float fast_exp2(float x) {
    float r;
    asm("v_exp_f32 %0, %1" : "=v"(r) : "v"(x));
    return r;
}

// ---------------- CSR build ----------------
__global__ void count_deg(const int* __restrict__ dst, int* __restrict__ deg,
                          int* __restrict__ hist) {
    if (blockIdx.x == 0 && threadIdx.x < 64) hist[threadIdx.x] = 0;
    int i = blockIdx.x * blockDim.x + threadIdx.x;
    if (i < N_EDGES) atomicAdd(&deg[dst[i]], 1);
}

// block scan of degrees; LDS-aggregated REVERSED degree histogram (heavy bucket first)
__global__ void scan1(const int* __restrict__ deg, int* __restrict__ row_ptr,
                      int* __restrict__ bsum, int* __restrict__ hist) {
    __shared__ int lhist[64];
    __shared__ int wtot[16];
    int t = threadIdx.x;
    if (t < 64) lhist[t] = 0;
    int i = blockIdx.x * SCAN_B + t;
    int lane = t & 63, wv = t >> 6;
    int v = (i < N_NODES) ? deg[i] : 0;
    __syncthreads();
    if (i < N_NODES) atomicAdd(&lhist[63 - min(v, 63)], 1);  // reversed key
    int incl = wave_incl_scan(v, lane);
    if (lane == 63) wtot[wv] = incl;
    __syncthreads();
    if (wv == 0) {
        int wval = (lane < 16) ? wtot[lane] : 0;
        int ws = wave_incl_scan(wval, lane);
        if (lane < 16) wtot[lane] = ws - wval;
    }
    __syncthreads();
    int excl = incl - v + wtot[wv];
    if (i < N_NODES) row_ptr[i] = excl;
    if (t == SCAN_B - 1) bsum[blockIdx.x] = excl + v;
    if (t < 64) atomicAdd(&hist[t], lhist[t]);
}

// finalize row_ptr/pos ; block 0 also turns hist into exclusive bucket offsets (binpos)
__global__ void scan3(int* __restrict__ row_ptr, const int* __restrict__ bsum,
                      int* __restrict__ pos, const int* __restrict__ hist,
                      int* __restrict__ binpos) {
    __shared__ int boff_s;
    int t = threadIdx.x;
    if (t < 64) {
        int v = (t < NSCAN_BLOCKS && t < (int)blockIdx.x) ? bsum[t] : 0;
#pragma unroll
        for (int m = 32; m >= 1; m >>= 1) v += __shfl_xor(v, m, 64);
        if (t == 0) boff_s = v;
    }
    if (blockIdx.x == 0 && t >= 64 && t < 128) {
        int lane = t - 64;
        int v = hist[lane];
        int incl = wave_incl_scan(v, lane);
        binpos[lane] = incl - v;
    }
    __syncthreads();
    int i = blockIdx.x * SCAN_B + t;
    if (i < N_NODES) {
        int r = row_ptr[i] + boff_s;
        row_ptr[i] = r;
        pos[i] = r;
    }
    if (i == 0) row_ptr[N_NODES] = N_EDGES;
}

// contention-free degree-bucket scatter (reversed key: heavy nodes land first in perm)
__global__ void bucket_nodes(const int* __restrict__ deg, int* __restrict__ binpos,
                             int* __restrict__ perm) {
    __shared__ int lhist[64], lbase[64];
    int t = threadIdx.x;
    if (t < 64) lhist[t] = 0;
    __syncthreads();
    int i = blockIdx.x * SCAN_B + t;
    int b = 0;
    if (i < N_NODES) {
        b = 63 - min(deg[i], 63);
        atomicAdd(&lhist[b], 1);
    }
    __syncthreads();
    if (t < 64) {
        lbase[t] = atomicAdd(&binpos[t], lhist[t]);
        lhist[t] = 0;
    }
    __syncthreads();
    if (i < N_NODES) {
        int r = atomicAdd(&lhist[b], 1);
        perm[lbase[b] + r] = i;
    }
}

__global__ void scatter_edges(const int* __restrict__ dst, const int* __restrict__ src,
                              int* __restrict__ pos, int* __restrict__ srcs) {
    int i = blockIdx.x * blockDim.x + threadIdx.x;
    if (i < N_EDGES) {
        int p = atomicAdd(&pos[dst[i]], 1);
        srcs[p] = src[i];
    }
}

// ---------------- pack 13 64x64 weight matrices into MFMA B-fragment order -------------
__global__ void pack_w(const float* __restrict__ w_in, const float* __restrict__ w_src,
                       const float* __restrict__ w_dst, unsigned short* __restrict__ wpk_hi,
                       unsigned short* __restrict__ wpk_lo) {
    int b = blockIdx.x;
    const float* W = (b == 0) ? w_in
                              : (b <= 6 ? w_src + (size_t)(b - 1) * 4096
                                        : w_dst + (size_t)(b - 7) * 4096);
    unsigned short* hi = wpk_hi + (size_t)b * 4096;
    unsigned short* lo = wpk_lo + (size_t)b * 4096;
    for (int idx = threadIdx.x; idx < 4096; idx += 256) {
        int t = idx >> 10;
        int s = (idx >> 9) & 1;
        int l = (idx >> 3) & 63;
        int j = idx & 7;
        int row = s * 32 + (l >> 4) * 8 + j;
        int col = t * 16 + (l & 15);
        float v = W[row * 64 + col];
        unsigned rh = bf16_rne(v);
        float hf = __uint_as_float(rh << 16);
        unsigned rl = bf16_rne(v - hf);
        hi[idx] = (unsigned short)rh;
        lo[idx] = (unsigned short)rl;
    }
}

// load 8 fp32 and split into bf16 hi/lo fragments
__device__ __forceinline__ void load_split8(const float* __restrict__ p, short8& hi, short8& lo) {
    float4 x0 = *(const float4*)p;
    float4 x1 = *(const float4*)(p + 4);
    float v[8] = {x0.x, x0.y, x0.z, x0.w, x1.x, x1.y, x1.z, x1.w};
#pragma unroll
    for (int j = 0; j < 8; ++j) {
        unsigned rh = bf16_rne(v[j]);
        float hf = __uint_as_float(rh << 16);
        unsigned rl = bf16_rne(v[j] - hf);
        hi[j] = (short)rh;
        lo[j] = (short)rl;
    }
}

// 16 output rows x 64 cols via 3-MFMA split-bf16 (fp32-accurate)
__device__ __forceinline__ void mfma_16rows(const short8 ah0, const short8 ah1, const short8 al0,
                                            const short8 al1,
                                            const unsigned short* __restrict__ whi,
                                            const unsigned short* __restrict__ wlo, int lane,
                                            f32x4 acc[4]) {
#pragma unroll
    for (int t = 0; t < 4; ++t) {
#pragma unroll
        for (int s = 0; s < 2; ++s) {
            const size_t boff = ((size_t)((t * 2 + s) * 64 + lane)) * 8;
            short8 bh = *(const short8*)(whi + boff);
            short8 bl = *(const short8*)(wlo + boff);
            short8 a_h = s ? ah1 : ah0;
            short8 a_l = s ? al1 : al0;
            acc[t] = __builtin_amdgcn_mfma_f32_16x16x32_bf16(a_h, bh, acc[t], 0, 0, 0);
            acc[t] = __builtin_amdgcn_mfma_f32_16x16x32_bf16(a_l, bh, acc[t], 0, 0, 0);
            acc[t] = __builtin_amdgcn_mfma_f32_16x16x32_bf16(a_h, bl, acc[t], 0, 0, 0);
        }
    }
}

// ---------------- input projection via MFMA: H = nodes@w_in + b ----------------
__global__ void mfma_in_proj(const float* __restrict__ X, const unsigned short* __restrict__ whi,
                             const unsigned short* __restrict__ wlo,
                             const float* __restrict__ bias, float* __restrict__ H) {
    int lane = threadIdx.x & 63, wv = threadIdx.x >> 6;
    int R = blockIdx.x * 64 + wv * 16;
    int arow = min(R + (lane & 15), N_NODES - 1);
    const float* p = X + (size_t)arow * 64 + (lane >> 4) * 8;
    short8 ah0, ah1, al0, al1;
    load_split8(p, ah0, al0);
    load_split8(p + 32, ah1, al1);
    f32x4 acc[4];
    f32x4 z = {0.f, 0.f, 0.f, 0.f};
#pragma unroll
    for (int t = 0; t < 4; ++t) acc[t] = z;
    mfma_16rows(ah0, ah1, al0, al1, whi, wlo, lane, acc);
    int crow = R + (lane >> 4) * 4;
#pragma unroll
    for (int t = 0; t < 4; ++t) {
        int col = t * 16 + (lane & 15);
        float bv = bias[col];
#pragma unroll
        for (int r = 0; r < 4; ++r) {
            int row = crow + r;
            if (row < N_NODES) H[(size_t)row * 64 + col] = acc[t][r] + bv;
        }
    }
}

// ---------------- dual projection: fs = h@Ws+bs, fd = h@Wd+bd; one A-load, two outputs --
__global__ void mfma_dual(const float* __restrict__ X, const unsigned short* __restrict__ wshi,
                          const unsigned short* __restrict__ wslo, const float* __restrict__ bs,
                          const unsigned short* __restrict__ wdhi,
                          const unsigned short* __restrict__ wdlo, const float* __restrict__ bd,
                          float* __restrict__ FS, float* __restrict__ FD) {
    int lane = threadIdx.x & 63, wv = threadIdx.x >> 6;
    int R = blockIdx.x * 64 + wv * 16;
    int arow = min(R + (lane & 15), N_NODES - 1);
    const float* p = X + (size_t)arow * 64 + (lane >> 4) * 8;
    short8 ah0, ah1, al0, al1;
    load_split8(p, ah0, al0);
    load_split8(p + 32, ah1, al1);
    f32x4 accS[4], accD[4];
    f32x4 z = {0.f, 0.f, 0.f, 0.f};
#pragma unroll
    for (int t = 0; t < 4; ++t) {
        accS[t] = z;
        accD[t] = z;
    }
    mfma_16rows(ah0, ah1, al0, al1, wshi, wslo, lane, accS);
    mfma_16rows(ah0, ah1, al0, al1, wdhi, wdlo, lane, accD);
    int crow = R + (lane >> 4) * 4;
#pragma unroll
    for (int t = 0; t < 4; ++t) {
        int col = t * 16 + (lane & 15);
        float bsv = bs[col], bdv = bd[col];
#pragma unroll
        for (int r = 0; r < 4; ++r) {
            int row = crow + r;
            if (row < N_NODES) {
                FS[(size_t)row * 64 + col] = accS[t][r] + bsv;
                FD[(size_t)row * 64 + col] = accD[t][r] + bdv;
            }
        }
    }
}

// ---------------- fused per-node: quarter-wave, 2 nodes/wave interleaved, DPP reduce ---
// lane = (q<<4)|ql ; quarter q owns edge stream 4t+q of BOTH nodes; ql holds feats 4ql..+3
// No-max softmax (shift-invariant); score reduce via DPP row-rotates (no DS in main loop).
#define WPB 4  // waves per block, 2 nodes per wave
__global__ void node_fused_kernel(const float* __restrict__ fs, const float* __restrict__ fd,
                                  const int* __restrict__ row_ptr, const int* __restrict__ srcs,
                                  const int* __restrict__ perm, const float* __restrict__ attn,
                                  const float* __restrict__ gamma, const float* __restrict__ beta,
                                  float* __restrict__ h) {
    __shared__ float xpose[WPB][2][64];
    int lane = threadIdx.x & 63;
    int wv = threadIdx.x >> 6;
    int q = lane >> 4;
    int ql = lane & 15;
    int f0 = ql << 2;
    int gw = blockIdx.x * WPB + wv;
    int iA = gw * 2;
    if (iA >= N_NODES) return;
    int iB = iA + 1;
    bool hasB = iB < N_NODES;
    int nA = perm[iA];
    int nB = hasB ? perm[iB] : nA;
    float gL = gamma[lane], bL = beta[lane];
    float hvalA = h[(size_t)nA * 64 + lane];
    float hvalB = h[(size_t)nB * 64 + lane];
    float4 a4 = *(const float4*)&attn[f0];
    a4.x *= LOG2E;
    a4.y *= LOG2E;
    a4.z *= LOG2E;
    a4.w *= LOG2E;
    int begA = row_ptr[nA], degA = row_ptr[nA + 1] - begA;
    int begB = row_ptr[nB], degB = row_ptr[nB + 1] - begB;
    float4 fdA = *(const float4*)&fd[(size_t)nA * 64 + f0];
    float4 fdB = *(const float4*)&fd[(size_t)nB * 64 + f0];
    float dA = 0.f, dB = 0.f;
    float4 accA = make_float4(0.f, 0.f, 0.f, 0.f), accB = accA;
    int degM = max(degA, degB);
    for (int c0 = 0; c0 < degM; c0 += 64) {
        int clA = min(64, degA - c0);  // may be <= 0
        int clB = min(64, degB - c0);
        int svA = (lane < clA) ? srcs[begA + c0 + lane] : 0;
        int svB = (lane < clB) ? srcs[begB + c0 + lane] : 0;
        int ntm = (max(clA, clB) + 3) >> 2;
        float4 zf = make_float4(0.f, 0.f, 0.f, 0.f);
        float4 rA0 = zf, rA1 = zf, rB0 = zf, rB1 = zf;
        int sA0 = __shfl(svA, q, 64);
        if (q < clA) rA0 = *(const float4*)&fs[(size_t)sA0 * 64 + f0];
        int sB0 = __shfl(svB, q, 64);
        if (q < clB) rB0 = *(const float4*)&fs[(size_t)sB0 * 64 + f0];
        int sA1 = __shfl(svA, (4 + q) & 63, 64);
        if (4 + q < clA) rA1 = *(const float4*)&fs[(size_t)sA1 * 64 + f0];
        int sB1 = __shfl(svB, (4 + q) & 63, 64);
        if (4 + q < clB) rB1 = *(const float4*)&fs[(size_t)sB1 * 64 + f0];
        for (int t = 0; t < ntm; ++t) {
            int eoff = 4 * t + q;
            bool vA = eoff < clA, vB = eoff < clB;
            float4 cA = rA0, cB = rB0;
            rA0 = rA1;
            rB0 = rB1;
            int e2 = 4 * (t + 2) + q;
            int sA2 = __shfl(svA, e2 & 63, 64);
            int sB2 = __shfl(svB, e2 & 63, 64);
            rA1 = zf;
            rB1 = zf;
            if (e2 < clA) rA1 = *(const float4*)&fs[(size_t)sA2 * 64 + f0];
            if (e2 < clB) rB1 = *(const float4*)&fs[(size_t)sB2 * 64 + f0];
            // two independent score chains (leaky + dot), DPP row-sum reduce
            float ax = cA.x + fdA.x, ay = cA.y + fdA.y, az = cA.z + fdA.z, aw = cA.w + fdA.w;
            float bx = cB.x + fdB.x, by = cB.y + fdB.y, bz = cB.z + fdB.z, bw = cB.w + fdB.w;
            ax = fmaxf(ax, NEG_SLOPE * ax);
            ay = fmaxf(ay, NEG_SLOPE * ay);
            az = fmaxf(az, NEG_SLOPE * az);
            aw = fmaxf(aw, NEG_SLOPE * aw);
            bx = fmaxf(bx, NEG_SLOPE * bx);
            by = fmaxf(by, NEG_SLOPE * by);
            bz = fmaxf(bz, NEG_SLOPE * bz);
            bw = fmaxf(bw, NEG_SLOPE * bw);
            float spA = fmaf(a4.x, ax, fmaf(a4.y, ay, fmaf(a4.z, az, a4.w * aw)));
            float spB = fmaf(a4.x, bx, fmaf(a4.y, by, fmaf(a4.z, bz, a4.w * bw)));
            spA = dpp_rowsum16(spA);
            spB = dpp_rowsum16(spB);
            float wA = vA ? fast_exp2(spA) : 0.f;
            float wB = vB ? fast_exp2(spB) : 0.f;
            dA += wA;
            dB += wB;
            accA.x = fmaf(wA, cA.x, accA.x);
            accA.y = fmaf(wA, cA.y, accA.y);
            accA.z = fmaf(wA, cA.z, accA.z);
            accA.w = fmaf(wA, cA.w, accA.w);
            accB.x = fmaf(wB, cB.x, accB.x);
            accB.y = fmaf(wB, cB.y, accB.y);
            accB.z = fmaf(wB, cB.z, accB.z);
            accB.w = fmaf(wB, cB.w, accB.w);
        }
    }
    // merge the 4 per-quarter partial sums for both nodes (pure adds)
#pragma unroll
    for (int msk = 16; msk <= 32; msk <<= 1) {
        dA += __shfl_xor(dA, msk, 64);
        dB += __shfl_xor(dB, msk, 64);
        accA.x += __shfl_xor(accA.x, msk, 64);
        accA.y += __shfl_xor(accA.y, msk, 64);
        accA.z += __shfl_xor(accA.z, msk, 64);
        accA.w += __shfl_xor(accA.w, msk, 64);
        accB.x += __shfl_xor(accB.x, msk, 64);
        accB.y += __shfl_xor(accB.y, msk, 64);
        accB.z += __shfl_xor(accB.z, msk, 64);
        accB.w += __shfl_xor(accB.w, msk, 64);
    }
    float invA = (dA > 0.f) ? 1.f / dA : 0.f;
    float invB = (dB > 0.f) ? 1.f / dB : 0.f;
    accA.x *= invA;
    accA.y *= invA;
    accA.z *= invA;
    accA.w *= invA;
    accB.x *= invB;
    accB.y *= invB;
    accB.z *= invB;
    accB.w *= invB;
    // transpose both to lane=feature layout via LDS (quarter 0 writes A, quarter 1 writes B)
    if (q == 0) *(float4*)&xpose[wv][0][f0] = accA;
    if (q == 1) *(float4*)&xpose[wv][1][f0] = accB;
    float valA = xpose[wv][0][lane];
    float valB = xpose[wv][1][lane];
    // layernorm + exact gelu + residual, two independent chains
    float meanA = wave_sum64_fast(valA) * 0.015625f;
    float meanB = wave_sum64_fast(valB) * 0.015625f;
    float devA = valA - meanA, devB = valB - meanB;
    float varA = wave_sum64_fast(devA * devA) * 0.015625f;
    float varB = wave_sum64_fast(devB * devB) * 0.015625f;
    float rstdA = rsqrtf(varA + LN_EPS), rstdB = rsqrtf(varB + LN_EPS);
    float tA = fmaf(devA * rstdA, gL, bL);
    float tB = fmaf(devB * rstdB, gL, bL);
    const float IS2 = 0.70710678118654752f;
    float gA = 0.5f * tA * (1.f + erff(tA * IS2));
    float gB = 0.5f * tB * (1.f + erff(tB * IS2));
    h[(size_t)nA * 64 + lane] = hvalA + gA;
    if (hasB) h[(size_t)nB * 64 + lane] = hvalB + gB;
}

// ---------------- output projection [n,64] @ [64,8] + b ----------------
__global__ void out_proj_kernel(const float* __restrict__ h, const float* __restrict__ W,
                                const float* __restrict__ b, float* __restrict__ out) {
    __shared__ float Ws[64 * 8];
    __shared__ float bs[8];
    __shared__ float Hs[32][65];
    int t = threadIdx.x;
    for (int i = t; i < 512; i += 256) Ws[i] = W[i];
    if (t < 8) bs[t] = b[t];
    int n0 = blockIdx.x * 32;
    for (int i = t; i < 32 * 64; i += 256) {
        int r = i >> 6, c = i & 63;
        int n = n0 + r;
        Hs[r][c] = (n < N_NODES) ? h[(size_t)n * 64 + c] : 0.f;
    }
    __syncthreads();
    int nl = t >> 3, o = t & 7;
    int n = n0 + nl;
    if (n >= N_NODES) return;
    float acc = bs[o];
#pragma unroll
    for (int k = 0; k < 64; ++k) acc = fmaf(Hs[nl][k], Ws[k * 8 + o], acc);
    out[(size_t)n * 8 + o] = acc;
}

extern "C" void kernel_launch(void* const* d_in, const int* in_sizes, int n_in,
                              void* d_out, int out_size, void* d_ws, size_t ws_size,
                              hipStream_t stream) {
    const float* nodes = (const float*)d_in[0];
    const int* src = (const int*)d_in[1];
    const int* dst = (const int*)d_in[2];
    const float* w_in = (const float*)d_in[3];
    const float* b_in = (const float*)d_in[4];
    const float* w_src = (const float*)d_in[5];
    const float* b_src = (const float*)d_in[6];
    const float* w_dst = (const float*)d_in[7];
    const float* b_dst = (const float*)d_in[8];
    const float* attn = (const float*)d_in[9];
    const float* gamma = (const float*)d_in[10];
    const float* beta = (const float*)d_in[11];
    const float* w_out = (const float*)d_in[12];
    const float* b_out = (const float*)d_in[13];
    float* out = (float*)d_out;

    char* ws = (char*)d_ws;
    size_t off = 0;
    auto alloc = [&](size_t bytes) {
        void* p = ws + off;
        off += (bytes + 255) & ~(size_t)255;
        return p;
    };
    float* h = (float*)alloc((size_t)N_NODES * 64 * 4);
    float* fs = (float*)alloc((size_t)N_NODES * 64 * 4);
    float* fd = (float*)alloc((size_t)N_NODES * 64 * 4);
    unsigned short* wpk_hi = (unsigned short*)alloc((size_t)13 * 4096 * 2);
    unsigned short* wpk_lo = (unsigned short*)alloc((size_t)13 * 4096 * 2);
    int* deg = (int*)alloc((size_t)N_NODES * 4);
    int* row_ptr = (int*)alloc((size_t)(N_NODES + 1) * 4);
    int* pos = (int*)alloc((size_t)N_NODES * 4);
    int* srcs = (int*)alloc((size_t)N_EDGES * 4);
    int* bsum = (int*)alloc((size_t)NSCAN_BLOCKS * 4);
    int* hist = (int*)alloc((size_t)64 * 4);
    int* binpos = (int*)alloc((size_t)64 * 4);
    int* perm = (int*)alloc((size_t)N_NODES * 4);

    // CSR by dst (graph static across layers); perm[] = nodes counting-sorted into 64
    // REVERSED degree buckets (heaviest first -> stragglers start early).
    hipMemsetAsync(deg, 0, (size_t)N_NODES * 4, stream);
    count_deg<<<(N_EDGES + 255) / 256, 256, 0, stream>>>(dst, deg, hist);
    scan1<<<NSCAN_BLOCKS, SCAN_B, 0, stream>>>(deg, row_ptr, bsum, hist);
    scan3<<<NSCAN_BLOCKS, SCAN_B, 0, stream>>>(row_ptr, bsum, pos, hist, binpos);
    bucket_nodes<<<NSCAN_BLOCKS, SCAN_B, 0, stream>>>(deg, binpos, perm);
    scatter_edges<<<(N_EDGES + 255) / 256, 256, 0, stream>>>(dst, src, pos, srcs);

    // weight packing (bf16 hi/lo, MFMA fragment order)
    pack_w<<<13, 256, 0, stream>>>(w_in, w_src, w_dst, wpk_hi, wpk_lo);

    // input projection (MFMA, split-bf16 = fp32 accuracy)
    mfma_in_proj<<<(N_NODES + 63) / 64, 256, 0, stream>>>(nodes, wpk_hi, wpk_lo, b_in, h);

    const int NF_GRID = (N_NODES + WPB * 2 - 1) / (WPB * 2);
    for (int l = 0; l < NLAYERS; ++l) {
        mfma_dual<<<(N_NODES + 63) / 64, 256, 0, stream>>>(
            h, wpk_hi + (size_t)(1 + l) * 4096, wpk_lo + (size_t)(1 + l) * 4096,
            b_src + (size_t)l * 64, wpk_hi + (size_t)(7 + l) * 4096,
            wpk_lo + (size_t)(7 + l) * 4096, b_dst + (size_t)l * 64, fs, fd);
        node_fused_kernel<<<NF_GRID, 256, 0, stream>>>(
            fs, fd, row_ptr, srcs, perm, attn + (size_t)l * 64, gamma + (size_t)l * 64,
            beta + (size_t)l * 64, h);
    }

    out_proj_kernel<<<(N_NODES + 31) / 32, 256, 0, stream>>>(h, w_out, b_out, out);
}

// Round 14
// 347.560 us; speedup vs baseline: 1.0263x; 1.0263x over previous
//
#include <hip/hip_runtime.h>
#include <math.h>

#define N_NODES 50000
#define N_EDGES 500000
#define NLAYERS 6
#define NEG_SLOPE 0.2f
#define LN_EPS 1e-5f
#define SCAN_B 1024
#define NSCAN_BLOCKS ((N_NODES + SCAN_B - 1) / SCAN_B)  // 49
#define LOG2E 1.4426950408889634f

typedef __attribute__((ext_vector_type(8))) short short8;
typedef __attribute__((ext_vector_type(4))) float f32x4;

__device__ __forceinline__ float wave_sum64(float v) {
#pragma unroll
    for (int m = 32; m >= 1; m >>= 1) v += __shfl_xor(v, m, 64);
    return v;
}

__device__ __forceinline__ int wave_incl_scan(int v, int lane) {
#pragma unroll
    for (int offs = 1; offs < 64; offs <<= 1) {
        int t = __shfl_up(v, offs, 64);
        if (lane >= offs) v += t;
    }
    return v;
}

__device__ __forceinline__ unsigned bf16_rne(float v) {
    unsigned u = __float_as_uint(v);
    return (u + 0x7fffu + ((u >> 16) & 1u)) >> 16;
}

__device__ __forceinline__ float fast_exp2(float x) {
    float r;
    asm("v_exp_f32 %0, %1" : "=v"(r) : "v"(x));
    return r;
}

__device__ __forceinline__ float4 bf4_to_f4(ushort4 u) {
    float4 r;
    r.x = __uint_as_float((unsigned)u.x << 16);
    r.y = __uint_as_float((unsigned)u.y << 16);
    r.z = __uint_as_float((unsigned)u.z << 16);
    r.w = __uint_as_float((unsigned)u.w << 16);
    return r;
}

// ---------------- CSR build ----------------
__global__ void count_deg(const int* __restrict__ dst, int* __restrict__ deg,
                          int* __restrict__ hist) {
    if (blockIdx.x == 0 && threadIdx.x < 64) hist[threadIdx.x] = 0;
    int i = blockIdx.x * blockDim.x + threadIdx.x;
    if (i < N_EDGES) atomicAdd(&deg[dst[i]], 1);
}

// block scan of degrees; LDS-aggregated degree histogram (64 global atomics per block)
__global__ void scan1(const int* __restrict__ deg, int* __restrict__ row_ptr,
                      int* __restrict__ bsum, int* __restrict__ hist) {
    __shared__ int lhist[64];
    __shared__ int wtot[16];
    int t = threadIdx.x;
    if (t < 64) lhist[t] = 0;
    int i = blockIdx.x * SCAN_B + t;
    int lane = t & 63, wv = t >> 6;
    int v = (i < N_NODES) ? deg[i] : 0;
    __syncthreads();
    if (i < N_NODES) atomicAdd(&lhist[min(v, 63)], 1);  // LDS atomic: cheap
    int incl = wave_incl_scan(v, lane);
    if (lane == 63) wtot[wv] = incl;
    __syncthreads();
    if (wv == 0) {
        int wval = (lane < 16) ? wtot[lane] : 0;
        int ws = wave_incl_scan(wval, lane);
        if (lane < 16) wtot[lane] = ws - wval;
    }
    __syncthreads();
    int excl = incl - v + wtot[wv];
    if (i < N_NODES) row_ptr[i] = excl;
    if (t == SCAN_B - 1) bsum[blockIdx.x] = excl + v;
    if (t < 64) atomicAdd(&hist[t], lhist[t]);  // 64 global atomics per block
}

// finalize row_ptr/pos ; block 0 also turns hist into exclusive bucket offsets (binpos)
__global__ void scan3(int* __restrict__ row_ptr, const int* __restrict__ bsum,
                      int* __restrict__ pos, const int* __restrict__ hist,
                      int* __restrict__ binpos) {
    __shared__ int boff_s;
    int t = threadIdx.x;
    if (t < 64) {
        int v = (t < NSCAN_BLOCKS && t < (int)blockIdx.x) ? bsum[t] : 0;
#pragma unroll
        for (int m = 32; m >= 1; m >>= 1) v += __shfl_xor(v, m, 64);
        if (t == 0) boff_s = v;
    }
    if (blockIdx.x == 0 && t >= 64 && t < 128) {
        int lane = t - 64;
        int v = hist[lane];
        int incl = wave_incl_scan(v, lane);
        binpos[lane] = incl - v;
    }
    __syncthreads();
    int i = blockIdx.x * SCAN_B + t;
    if (i < N_NODES) {
        int r = row_ptr[i] + boff_s;
        row_ptr[i] = r;
        pos[i] = r;
    }
    if (i == 0) row_ptr[N_NODES] = N_EDGES;
}

// contention-free degree-bucket scatter: LDS hist -> 64 reserve atomics -> LDS-rank scatter
__global__ void bucket_nodes(const int* __restrict__ deg, int* __restrict__ binpos,
                             int* __restrict__ perm) {
    __shared__ int lhist[64], lbase[64];
    int t = threadIdx.x;
    if (t < 64) lhist[t] = 0;
    __syncthreads();
    int i = blockIdx.x * SCAN_B + t;
    int b = 0;
    if (i < N_NODES) {
        b = min(deg[i], 63);
        atomicAdd(&lhist[b], 1);
    }
    __syncthreads();
    if (t < 64) {
        lbase[t] = atomicAdd(&binpos[t], lhist[t]);  // reserve this block's chunk of bin t
        lhist[t] = 0;                                // reuse as local rank counter
    }
    __syncthreads();
    if (i < N_NODES) {
        int r = atomicAdd(&lhist[b], 1);  // LDS atomic: local rank
        perm[lbase[b] + r] = i;
    }
}

__global__ void scatter_edges(const int* __restrict__ dst, const int* __restrict__ src,
                              int* __restrict__ pos, int* __restrict__ srcs) {
    int i = blockIdx.x * blockDim.x + threadIdx.x;
    if (i < N_EDGES) {
        int p = atomicAdd(&pos[dst[i]], 1);
        srcs[p] = src[i];
    }
}

// ---------------- pack 13 64x64 weight matrices into MFMA B-fragment order -------------
__global__ void pack_w(const float* __restrict__ w_in, const float* __restrict__ w_src,
                       const float* __restrict__ w_dst, unsigned short* __restrict__ wpk_hi,
                       unsigned short* __restrict__ wpk_lo) {
    int b = blockIdx.x;
    const float* W = (b == 0) ? w_in
                              : (b <= 6 ? w_src + (size_t)(b - 1) * 4096
                                        : w_dst + (size_t)(b - 7) * 4096);
    unsigned short* hi = wpk_hi + (size_t)b * 4096;
    unsigned short* lo = wpk_lo + (size_t)b * 4096;
    for (int idx = threadIdx.x; idx < 4096; idx += 256) {
        int t = idx >> 10;
        int s = (idx >> 9) & 1;
        int l = (idx >> 3) & 63;
        int j = idx & 7;
        int row = s * 32 + (l >> 4) * 8 + j;
        int col = t * 16 + (l & 15);
        float v = W[row * 64 + col];
        unsigned rh = bf16_rne(v);
        float hf = __uint_as_float(rh << 16);
        unsigned rl = bf16_rne(v - hf);
        hi[idx] = (unsigned short)rh;
        lo[idx] = (unsigned short)rl;
    }
}

// load 8 fp32 and split into bf16 hi/lo fragments
__device__ __forceinline__ void load_split8(const float* __restrict__ p, short8& hi, short8& lo) {
    float4 x0 = *(const float4*)p;
    float4 x1 = *(const float4*)(p + 4);
    float v[8] = {x0.x, x0.y, x0.z, x0.w, x1.x, x1.y, x1.z, x1.w};
#pragma unroll
    for (int j = 0; j < 8; ++j) {
        unsigned rh = bf16_rne(v[j]);
        float hf = __uint_as_float(rh << 16);
        unsigned rl = bf16_rne(v[j] - hf);
        hi[j] = (short)rh;
        lo[j] = (short)rl;
    }
}

// 16 output rows x 64 cols via 3-MFMA split-bf16 (fp32-accurate)
__device__ __forceinline__ void mfma_16rows(const short8 ah0, const short8 ah1, const short8 al0,
                                            const short8 al1,
                                            const unsigned short* __restrict__ whi,
                                            const unsigned short* __restrict__ wlo, int lane,
                                            f32x4 acc[4]) {
#pragma unroll
    for (int t = 0; t < 4; ++t) {
#pragma unroll
        for (int s = 0; s < 2; ++s) {
            const size_t boff = ((size_t)((t * 2 + s) * 64 + lane)) * 8;
            short8 bh = *(const short8*)(whi + boff);
            short8 bl = *(const short8*)(wlo + boff);
            short8 a_h = s ? ah1 : ah0;
            short8 a_l = s ? al1 : al0;
            acc[t] = __builtin_amdgcn_mfma_f32_16x16x32_bf16(a_h, bh, acc[t], 0, 0, 0);
            acc[t] = __builtin_amdgcn_mfma_f32_16x16x32_bf16(a_l, bh, acc[t], 0, 0, 0);
            acc[t] = __builtin_amdgcn_mfma_f32_16x16x32_bf16(a_h, bl, acc[t], 0, 0, 0);
        }
    }
}

// ---------------- input projection via MFMA: H = nodes@w_in + b ----------------
__global__ void mfma_in_proj(const float* __restrict__ X, const unsigned short* __restrict__ whi,
                             const unsigned short* __restrict__ wlo,
                             const float* __restrict__ bias, float* __restrict__ H) {
    int lane = threadIdx.x & 63, wv = threadIdx.x >> 6;
    int R = blockIdx.x * 64 + wv * 16;
    int arow = min(R + (lane & 15), N_NODES - 1);
    const float* p = X + (size_t)arow * 64 + (lane >> 4) * 8;
    short8 ah0, ah1, al0, al1;
    load_split8(p, ah0, al0);
    load_split8(p + 32, ah1, al1);
    f32x4 acc[4];
    f32x4 z = {0.f, 0.f, 0.f, 0.f};
#pragma unroll
    for (int t = 0; t < 4; ++t) acc[t] = z;
    mfma_16rows(ah0, ah1, al0, al1, whi, wlo, lane, acc);
    int crow = R + (lane >> 4) * 4;
#pragma unroll
    for (int t = 0; t < 4; ++t) {
        int col = t * 16 + (lane & 15);
        float bv = bias[col];
#pragma unroll
        for (int r = 0; r < 4; ++r) {
            int row = crow + r;
            if (row < N_NODES) H[(size_t)row * 64 + col] = acc[t][r] + bv;
        }
    }
}

// ---------------- dual projection: fs (bf16) = h@Ws+bs, fd (fp32) = h@Wd+bd -------------
__global__ void mfma_dual(const float* __restrict__ X, const unsigned short* __restrict__ wshi,
                          const unsigned short* __restrict__ wslo, const float* __restrict__ bs,
                          const unsigned short* __restrict__ wdhi,
                          const unsigned short* __restrict__ wdlo, const float* __restrict__ bd,
                          unsigned short* __restrict__ FS, float* __restrict__ FD) {
    int lane = threadIdx.x & 63, wv = threadIdx.x >> 6;
    int R = blockIdx.x * 64 + wv * 16;
    int arow = min(R + (lane & 15), N_NODES - 1);
    const float* p = X + (size_t)arow * 64 + (lane >> 4) * 8;
    short8 ah0, ah1, al0, al1;
    load_split8(p, ah0, al0);
    load_split8(p + 32, ah1, al1);
    f32x4 accS[4], accD[4];
    f32x4 z = {0.f, 0.f, 0.f, 0.f};
#pragma unroll
    for (int t = 0; t < 4; ++t) {
        accS[t] = z;
        accD[t] = z;
    }
    mfma_16rows(ah0, ah1, al0, al1, wshi, wslo, lane, accS);
    mfma_16rows(ah0, ah1, al0, al1, wdhi, wdlo, lane, accD);
    int crow = R + (lane >> 4) * 4;
#pragma unroll
    for (int t = 0; t < 4; ++t) {
        int col = t * 16 + (lane & 15);
        float bsv = bs[col], bdv = bd[col];
#pragma unroll
        for (int r = 0; r < 4; ++r) {
            int row = crow + r;
            if (row < N_NODES) {
                FS[(size_t)row * 64 + col] = (unsigned short)bf16_rne(accS[t][r] + bsv);
                FD[(size_t)row * 64 + col] = accD[t][r] + bdv;
            }
        }
    }
}

// ---------------- fused per-node, quarter-wave, 1 node/wave, no-max softmax, bf16 fs ---
// lane = (q<<4)|ql ; quarter q owns edge stream 4t+q ; lane ql holds feats 4ql..+3
// Softmax computed WITHOUT online max (shift-invariant; |score| << 127 in log2 domain).
#define WPB 4  // waves per block, 1 node per wave
__global__ void node_fused_kernel(const unsigned short* __restrict__ fs,
                                  const float* __restrict__ fd, const int* __restrict__ row_ptr,
                                  const int* __restrict__ srcs, const int* __restrict__ perm,
                                  const float* __restrict__ attn, const float* __restrict__ gamma,
                                  const float* __restrict__ beta, float* __restrict__ h) {
    __shared__ float xpose[WPB][64];
    int lane = threadIdx.x & 63;
    int wv = threadIdx.x >> 6;
    int q = lane >> 4;
    int ql = lane & 15;
    int f0 = ql << 2;
    int idx = blockIdx.x * WPB + wv;
    if (idx >= N_NODES) return;
    int n = perm[idx];  // degree-bucketed
    float gL = gamma[lane], bL = beta[lane];
    float hval = h[(size_t)n * 64 + lane];  // early issue, coalesced
    float4 a4 = *(const float4*)&attn[f0];
    a4.x *= LOG2E;
    a4.y *= LOG2E;
    a4.z *= LOG2E;
    a4.w *= LOG2E;
    int beg = row_ptr[n], end = row_ptr[n + 1];
    int deg = end - beg;
    float4 fd4 = *(const float4*)&fd[(size_t)n * 64 + f0];
    float d = 0.f;
    float4 acc = make_float4(0.f, 0.f, 0.f, 0.f);
    for (int c0 = 0; c0 < deg; c0 += 64) {
        int cl = min(64, deg - c0);
        int sv = (lane < cl) ? srcs[beg + c0 + lane] : 0;
        int nt = (cl + 3) >> 2;
        ushort4 rowA = make_ushort4(0, 0, 0, 0), rowB = rowA;
        int sid0 = __shfl(sv, q, 64);
        if (q < cl) rowA = *(const ushort4*)&fs[(size_t)sid0 * 64 + f0];
        int sid1 = __shfl(sv, (4 + q) & 63, 64);
        if (4 + q < cl) rowB = *(const ushort4*)&fs[(size_t)sid1 * 64 + f0];
        for (int t = 0; t < nt; ++t) {
            int eoff = 4 * t + q;
            bool valid = eoff < cl;
            float4 cur = bf4_to_f4(rowA);
            rowA = rowB;
            int e2 = 4 * (t + 2) + q;
            int sid2 = __shfl(sv, e2 & 63, 64);
            if (e2 < cl) rowB = *(const ushort4*)&fs[(size_t)sid2 * 64 + f0];  // prefetch
            float vx = cur.x + fd4.x, vy = cur.y + fd4.y;
            float vz = cur.z + fd4.z, vw = cur.w + fd4.w;
            vx = fmaxf(vx, NEG_SLOPE * vx);
            vy = fmaxf(vy, NEG_SLOPE * vy);
            vz = fmaxf(vz, NEG_SLOPE * vz);
            vw = fmaxf(vw, NEG_SLOPE * vw);
            float sp = fmaf(a4.x, vx, fmaf(a4.y, vy, fmaf(a4.z, vz, a4.w * vw)));
            sp += __shfl_xor(sp, 1, 64);
            sp += __shfl_xor(sp, 2, 64);
            sp += __shfl_xor(sp, 4, 64);
            sp += __shfl_xor(sp, 8, 64);
            float w = valid ? fast_exp2(sp) : 0.f;  // no-max softmax: shift-invariant
            d += w;
            acc.x = fmaf(w, cur.x, acc.x);
            acc.y = fmaf(w, cur.y, acc.y);
            acc.z = fmaf(w, cur.z, acc.z);
            acc.w = fmaf(w, cur.w, acc.w);
        }
    }
    // merge the 4 per-quarter partial sums (pure additions, no max bookkeeping)
    d += __shfl_xor(d, 16, 64);
    d += __shfl_xor(d, 32, 64);
    acc.x += __shfl_xor(acc.x, 16, 64);
    acc.y += __shfl_xor(acc.y, 16, 64);
    acc.z += __shfl_xor(acc.z, 16, 64);
    acc.w += __shfl_xor(acc.w, 16, 64);
    acc.x += __shfl_xor(acc.x, 32, 64);
    acc.y += __shfl_xor(acc.y, 32, 64);
    acc.z += __shfl_xor(acc.z, 32, 64);
    acc.w += __shfl_xor(acc.w, 32, 64);
    float inv = (d > 0.f) ? 1.f / d : 0.f;
    acc.x *= inv;
    acc.y *= inv;
    acc.z *= inv;
    acc.w *= inv;
    // transpose to lane=feature layout via LDS (same-wave, ordered)
    if (q == 0) *(float4*)&xpose[wv][f0] = acc;
    float val = xpose[wv][lane];
    // layernorm + exact gelu + residual, one feature per lane
    float mean = wave_sum64(val) * 0.015625f;
    float dev = val - mean;
    float var = wave_sum64(dev * dev) * 0.015625f;
    float rstd = rsqrtf(var + LN_EPS);
    float tval = fmaf(dev * rstd, gL, bL);
    float g = 0.5f * tval * (1.f + erff(tval * 0.70710678118654752f));
    h[(size_t)n * 64 + lane] = hval + g;
}

// ---------------- output projection [n,64] @ [64,8] + b ----------------
__global__ void out_proj_kernel(const float* __restrict__ h, const float* __restrict__ W,
                                const float* __restrict__ b, float* __restrict__ out) {
    __shared__ float Ws[64 * 8];
    __shared__ float bs[8];
    __shared__ float Hs[32][65];
    int t = threadIdx.x;
    for (int i = t; i < 512; i += 256) Ws[i] = W[i];
    if (t < 8) bs[t] = b[t];
    int n0 = blockIdx.x * 32;
    for (int i = t; i < 32 * 64; i += 256) {
        int r = i >> 6, c = i & 63;
        int n = n0 + r;
        Hs[r][c] = (n < N_NODES) ? h[(size_t)n * 64 + c] : 0.f;
    }
    __syncthreads();
    int nl = t >> 3, o = t & 7;
    int n = n0 + nl;
    if (n >= N_NODES) return;
    float acc = bs[o];
#pragma unroll
    for (int k = 0; k < 64; ++k) acc = fmaf(Hs[nl][k], Ws[k * 8 + o], acc);
    out[(size_t)n * 8 + o] = acc;
}

extern "C" void kernel_launch(void* const* d_in, const int* in_sizes, int n_in,
                              void* d_out, int out_size, void* d_ws, size_t ws_size,
                              hipStream_t stream) {
    const float* nodes = (const float*)d_in[0];
    const int* src = (const int*)d_in[1];
    const int* dst = (const int*)d_in[2];
    const float* w_in = (const float*)d_in[3];
    const float* b_in = (const float*)d_in[4];
    const float* w_src = (const float*)d_in[5];
    const float* b_src = (const float*)d_in[6];
    const float* w_dst = (const float*)d_in[7];
    const float* b_dst = (const float*)d_in[8];
    const float* attn = (const float*)d_in[9];
    const float* gamma = (const float*)d_in[10];
    const float* beta = (const float*)d_in[11];
    const float* w_out = (const float*)d_in[12];
    const float* b_out = (const float*)d_in[13];
    float* out = (float*)d_out;

    char* ws = (char*)d_ws;
    size_t off = 0;
    auto alloc = [&](size_t bytes) {
        void* p = ws + off;
        off += (bytes + 255) & ~(size_t)255;
        return p;
    };
    float* h = (float*)alloc((size_t)N_NODES * 64 * 4);
    unsigned short* fs = (unsigned short*)alloc((size_t)N_NODES * 64 * 2);
    float* fd = (float*)alloc((size_t)N_NODES * 64 * 4);
    unsigned short* wpk_hi = (unsigned short*)alloc((size_t)13 * 4096 * 2);
    unsigned short* wpk_lo = (unsigned short*)alloc((size_t)13 * 4096 * 2);
    int* deg = (int*)alloc((size_t)N_NODES * 4);
    int* row_ptr = (int*)alloc((size_t)(N_NODES + 1) * 4);
    int* pos = (int*)alloc((size_t)N_NODES * 4);
    int* srcs = (int*)alloc((size_t)N_EDGES * 4);
    int* bsum = (int*)alloc((size_t)NSCAN_BLOCKS * 4);
    int* hist = (int*)alloc((size_t)64 * 4);
    int* binpos = (int*)alloc((size_t)64 * 4);
    int* perm = (int*)alloc((size_t)N_NODES * 4);

    // CSR by dst (graph static across layers); srcs[] = src id in CSR slot order;
    // perm[] = nodes counting-sorted into 64 degree buckets, contention-free build.
    hipMemsetAsync(deg, 0, (size_t)N_NODES * 4, stream);
    count_deg<<<(N_EDGES + 255) / 256, 256, 0, stream>>>(dst, deg, hist);
    scan1<<<NSCAN_BLOCKS, SCAN_B, 0, stream>>>(deg, row_ptr, bsum, hist);
    scan3<<<NSCAN_BLOCKS, SCAN_B, 0, stream>>>(row_ptr, bsum, pos, hist, binpos);
    bucket_nodes<<<NSCAN_BLOCKS, SCAN_B, 0, stream>>>(deg, binpos, perm);
    scatter_edges<<<(N_EDGES + 255) / 256, 256, 0, stream>>>(dst, src, pos, srcs);

    // weight packing (bf16 hi/lo, MFMA fragment order)
    pack_w<<<13, 256, 0, stream>>>(w_in, w_src, w_dst, wpk_hi, wpk_lo);

    // input projection (MFMA, split-bf16 = fp32 accuracy)
    mfma_in_proj<<<(N_NODES + 63) / 64, 256, 0, stream>>>(nodes, wpk_hi, wpk_lo, b_in, h);

    for (int l = 0; l < NLAYERS; ++l) {
        mfma_dual<<<(N_NODES + 63) / 64, 256, 0, stream>>>(
            h, wpk_hi + (size_t)(1 + l) * 4096, wpk_lo + (size_t)(1 + l) * 4096,
            b_src + (size_t)l * 64, wpk_hi + (size_t)(7 + l) * 4096,
            wpk_lo + (size_t)(7 + l) * 4096, b_dst + (size_t)l * 64, fs, fd);
        node_fused_kernel<<<(N_NODES + WPB - 1) / WPB, 256, 0, stream>>>(
            fs, fd, row_ptr, srcs, perm, attn + (size_t)l * 64, gamma + (size_t)l * 64,
            beta + (size_t)l * 64, h);
    }

    out_proj_kernel<<<(N_NODES + 31) / 32, 256, 0, stream>>>(h, w_out, b_out, out);
}

// Round 15
// 346.655 us; speedup vs baseline: 1.0290x; 1.0026x over previous
//
#include <hip/hip_runtime.h>
#include <math.h>

#define N_NODES 50000
#define N_EDGES 500000
#define NLAYERS 6
#define NEG_SLOPE 0.2f
#define LN_EPS 1e-5f
#define SCAN_B 1024
#define NSCAN_BLOCKS ((N_NODES + SCAN_B - 1) / SCAN_B)  // 49
#define LOG2E 1.4426950408889634f

typedef __attribute__((ext_vector_type(8))) short short8;
typedef __attribute__((ext_vector_type(4))) float f32x4;

__device__ __forceinline__ float wave_sum64(float v) {
#pragma unroll
    for (int m = 32; m >= 1; m >>= 1) v += __shfl_xor(v, m, 64);
    return v;
}

__device__ __forceinline__ int wave_incl_scan(int v, int lane) {
#pragma unroll
    for (int offs = 1; offs < 64; offs <<= 1) {
        int t = __shfl_up(v, offs, 64);
        if (lane >= offs) v += t;
    }
    return v;
}

__device__ __forceinline__ unsigned bf16_rne(float v) {
    unsigned u = __float_as_uint(v);
    return (u + 0x7fffu + ((u >> 16) & 1u)) >> 16;
}

__device__ __forceinline__ float fast_exp2(float x) {
    float r;
    asm("v_exp_f32 %0, %1" : "=v"(r) : "v"(x));
    return r;
}

__device__ __forceinline__ float4 bf4_to_f4(ushort4 u) {
    float4 r;
    r.x = __uint_as_float((unsigned)u.x << 16);
    r.y = __uint_as_float((unsigned)u.y << 16);
    r.z = __uint_as_float((unsigned)u.z << 16);
    r.w = __uint_as_float((unsigned)u.w << 16);
    return r;
}

// ---------------- CSR build in PERMUTED node space ----------------
__global__ void count_deg(const int* __restrict__ dst, int* __restrict__ deg,
                          int* __restrict__ hist) {
    if (blockIdx.x == 0 && threadIdx.x < 64) hist[threadIdx.x] = 0;
    int i = blockIdx.x * blockDim.x + threadIdx.x;
    if (i < N_EDGES) atomicAdd(&deg[dst[i]], 1);
}

// degree histogram: LDS-aggregated, 64 global atomics per block
__global__ void histo(const int* __restrict__ deg, int* __restrict__ hist) {
    __shared__ int lhist[64];
    int t = threadIdx.x;
    if (t < 64) lhist[t] = 0;
    __syncthreads();
    int i = blockIdx.x * SCAN_B + t;
    if (i < N_NODES) atomicAdd(&lhist[min(deg[i], 63)], 1);
    __syncthreads();
    if (t < 64) atomicAdd(&hist[t], lhist[t]);
}

// exclusive scan of 64 bucket counts
__global__ void binscan(const int* __restrict__ hist, int* __restrict__ binpos) {
    int lane = threadIdx.x;
    int v = hist[lane];
    int incl = wave_incl_scan(v, lane);
    binpos[lane] = incl - v;
}

// contention-free degree-bucket scatter: perm (idx->orig) and inv_perm (orig->idx)
__global__ void bucket_nodes(const int* __restrict__ deg, int* __restrict__ binpos,
                             int* __restrict__ perm, int* __restrict__ inv_perm) {
    __shared__ int lhist[64], lbase[64];
    int t = threadIdx.x;
    if (t < 64) lhist[t] = 0;
    __syncthreads();
    int i = blockIdx.x * SCAN_B + t;
    int b = 0;
    if (i < N_NODES) {
        b = min(deg[i], 63);
        atomicAdd(&lhist[b], 1);
    }
    __syncthreads();
    if (t < 64) {
        lbase[t] = atomicAdd(&binpos[t], lhist[t]);
        lhist[t] = 0;
    }
    __syncthreads();
    if (i < N_NODES) {
        int r = atomicAdd(&lhist[b], 1);
        int p = lbase[b] + r;
        perm[p] = i;
        inv_perm[i] = p;
    }
}

// block scan of PERMUTED degrees -> row_ptr_p partials + block sums
__global__ void scan1p(const int* __restrict__ deg, const int* __restrict__ perm,
                       int* __restrict__ row_ptr_p, int* __restrict__ bsum) {
    __shared__ int wtot[16];
    int t = threadIdx.x;
    int i = blockIdx.x * SCAN_B + t;
    int lane = t & 63, wv = t >> 6;
    int v = (i < N_NODES) ? deg[perm[i]] : 0;
    int incl = wave_incl_scan(v, lane);
    if (lane == 63) wtot[wv] = incl;
    __syncthreads();
    if (wv == 0) {
        int wval = (lane < 16) ? wtot[lane] : 0;
        int ws = wave_incl_scan(wval, lane);
        if (lane < 16) wtot[lane] = ws - wval;
    }
    __syncthreads();
    int excl = incl - v + wtot[wv];
    if (i < N_NODES) row_ptr_p[i] = excl;
    if (t == SCAN_B - 1) bsum[blockIdx.x] = excl + v;
}

// finalize row_ptr_p / pos_p (each block redundantly reduces preceding block sums)
__global__ void scan3p(int* __restrict__ row_ptr_p, const int* __restrict__ bsum,
                       int* __restrict__ pos_p) {
    __shared__ int boff_s;
    int t = threadIdx.x;
    if (t < 64) {
        int v = (t < NSCAN_BLOCKS && t < (int)blockIdx.x) ? bsum[t] : 0;
#pragma unroll
        for (int m = 32; m >= 1; m >>= 1) v += __shfl_xor(v, m, 64);
        if (t == 0) boff_s = v;
    }
    __syncthreads();
    int i = blockIdx.x * SCAN_B + t;
    if (i < N_NODES) {
        int r = row_ptr_p[i] + boff_s;
        row_ptr_p[i] = r;
        pos_p[i] = r;
    }
    if (i == 0) row_ptr_p[N_NODES] = N_EDGES;
}

// edge scatter into permuted CSR; src ids pre-translated to permuted space
__global__ void scatter_edges(const int* __restrict__ dst, const int* __restrict__ src,
                              const int* __restrict__ inv_perm, int* __restrict__ pos_p,
                              int* __restrict__ srcs_p) {
    int i = blockIdx.x * blockDim.x + threadIdx.x;
    if (i < N_EDGES) {
        int dp = inv_perm[dst[i]];
        int p = atomicAdd(&pos_p[dp], 1);
        srcs_p[p] = inv_perm[src[i]];
    }
}

// ---------------- pack 13 64x64 weight matrices into MFMA B-fragment order -------------
__global__ void pack_w(const float* __restrict__ w_in, const float* __restrict__ w_src,
                       const float* __restrict__ w_dst, unsigned short* __restrict__ wpk_hi,
                       unsigned short* __restrict__ wpk_lo) {
    int b = blockIdx.x;
    const float* W = (b == 0) ? w_in
                              : (b <= 6 ? w_src + (size_t)(b - 1) * 4096
                                        : w_dst + (size_t)(b - 7) * 4096);
    unsigned short* hi = wpk_hi + (size_t)b * 4096;
    unsigned short* lo = wpk_lo + (size_t)b * 4096;
    for (int idx = threadIdx.x; idx < 4096; idx += 256) {
        int t = idx >> 10;
        int s = (idx >> 9) & 1;
        int l = (idx >> 3) & 63;
        int j = idx & 7;
        int row = s * 32 + (l >> 4) * 8 + j;
        int col = t * 16 + (l & 15);
        float v = W[row * 64 + col];
        unsigned rh = bf16_rne(v);
        float hf = __uint_as_float(rh << 16);
        unsigned rl = bf16_rne(v - hf);
        hi[idx] = (unsigned short)rh;
        lo[idx] = (unsigned short)rl;
    }
}

// load 8 fp32 and split into bf16 hi/lo fragments
__device__ __forceinline__ void load_split8(const float* __restrict__ p, short8& hi, short8& lo) {
    float4 x0 = *(const float4*)p;
    float4 x1 = *(const float4*)(p + 4);
    float v[8] = {x0.x, x0.y, x0.z, x0.w, x1.x, x1.y, x1.z, x1.w};
#pragma unroll
    for (int j = 0; j < 8; ++j) {
        unsigned rh = bf16_rne(v[j]);
        float hf = __uint_as_float(rh << 16);
        unsigned rl = bf16_rne(v[j] - hf);
        hi[j] = (short)rh;
        lo[j] = (short)rl;
    }
}

// 16 output rows x 64 cols via 3-MFMA split-bf16 (fp32-accurate)
__device__ __forceinline__ void mfma_16rows(const short8 ah0, const short8 ah1, const short8 al0,
                                            const short8 al1,
                                            const unsigned short* __restrict__ whi,
                                            const unsigned short* __restrict__ wlo, int lane,
                                            f32x4 acc[4]) {
#pragma unroll
    for (int t = 0; t < 4; ++t) {
#pragma unroll
        for (int s = 0; s < 2; ++s) {
            const size_t boff = ((size_t)((t * 2 + s) * 64 + lane)) * 8;
            short8 bh = *(const short8*)(whi + boff);
            short8 bl = *(const short8*)(wlo + boff);
            short8 a_h = s ? ah1 : ah0;
            short8 a_l = s ? al1 : al0;
            acc[t] = __builtin_amdgcn_mfma_f32_16x16x32_bf16(a_h, bh, acc[t], 0, 0, 0);
            acc[t] = __builtin_amdgcn_mfma_f32_16x16x32_bf16(a_l, bh, acc[t], 0, 0, 0);
            acc[t] = __builtin_amdgcn_mfma_f32_16x16x32_bf16(a_h, bl, acc[t], 0, 0, 0);
        }
    }
}

// ---------------- input projection via MFMA: h_p[idx] = nodes[perm[idx]]@w_in + b ------
__global__ void mfma_in_proj(const float* __restrict__ X, const int* __restrict__ perm,
                             const unsigned short* __restrict__ whi,
                             const unsigned short* __restrict__ wlo,
                             const float* __restrict__ bias, float* __restrict__ H) {
    int lane = threadIdx.x & 63, wv = threadIdx.x >> 6;
    int R = blockIdx.x * 64 + wv * 16;
    int arow = perm[min(R + (lane & 15), N_NODES - 1)];  // permuted input gather (one-time)
    const float* p = X + (size_t)arow * 64 + (lane >> 4) * 8;
    short8 ah0, ah1, al0, al1;
    load_split8(p, ah0, al0);
    load_split8(p + 32, ah1, al1);
    f32x4 acc[4];
    f32x4 z = {0.f, 0.f, 0.f, 0.f};
#pragma unroll
    for (int t = 0; t < 4; ++t) acc[t] = z;
    mfma_16rows(ah0, ah1, al0, al1, whi, wlo, lane, acc);
    int crow = R + (lane >> 4) * 4;
#pragma unroll
    for (int t = 0; t < 4; ++t) {
        int col = t * 16 + (lane & 15);
        float bv = bias[col];
#pragma unroll
        for (int r = 0; r < 4; ++r) {
            int row = crow + r;
            if (row < N_NODES) H[(size_t)row * 64 + col] = acc[t][r] + bv;
        }
    }
}

// ---------------- dual projection: fs (bf16) = h@Ws+bs, fd (fp32) = h@Wd+bd -------------
__global__ void mfma_dual(const float* __restrict__ X, const unsigned short* __restrict__ wshi,
                          const unsigned short* __restrict__ wslo, const float* __restrict__ bs,
                          const unsigned short* __restrict__ wdhi,
                          const unsigned short* __restrict__ wdlo, const float* __restrict__ bd,
                          unsigned short* __restrict__ FS, float* __restrict__ FD) {
    int lane = threadIdx.x & 63, wv = threadIdx.x >> 6;
    int R = blockIdx.x * 64 + wv * 16;
    int arow = min(R + (lane & 15), N_NODES - 1);
    const float* p = X + (size_t)arow * 64 + (lane >> 4) * 8;
    short8 ah0, ah1, al0, al1;
    load_split8(p, ah0, al0);
    load_split8(p + 32, ah1, al1);
    f32x4 accS[4], accD[4];
    f32x4 z = {0.f, 0.f, 0.f, 0.f};
#pragma unroll
    for (int t = 0; t < 4; ++t) {
        accS[t] = z;
        accD[t] = z;
    }
    mfma_16rows(ah0, ah1, al0, al1, wshi, wslo, lane, accS);
    mfma_16rows(ah0, ah1, al0, al1, wdhi, wdlo, lane, accD);
    int crow = R + (lane >> 4) * 4;
#pragma unroll
    for (int t = 0; t < 4; ++t) {
        int col = t * 16 + (lane & 15);
        float bsv = bs[col], bdv = bd[col];
#pragma unroll
        for (int r = 0; r < 4; ++r) {
            int row = crow + r;
            if (row < N_NODES) {
                FS[(size_t)row * 64 + col] = (unsigned short)bf16_rne(accS[t][r] + bsv);
                FD[(size_t)row * 64 + col] = accD[t][r] + bdv;
            }
        }
    }
}

// ---------------- fused per-node (permuted space): quarter-wave, no-max softmax --------
// All per-node arrays (row_ptr_p, srcs_p, fd, h) are coalesced in idx; only fs[src] random.
#define WPB 4  // waves per block, 1 node per wave
__global__ void node_fused_kernel(const unsigned short* __restrict__ fs,
                                  const float* __restrict__ fd, const int* __restrict__ row_ptr,
                                  const int* __restrict__ srcs, const float* __restrict__ attn,
                                  const float* __restrict__ gamma, const float* __restrict__ beta,
                                  float* __restrict__ h) {
    __shared__ float xpose[WPB][64];
    int lane = threadIdx.x & 63;
    int wv = threadIdx.x >> 6;
    int q = lane >> 4;
    int ql = lane & 15;
    int f0 = ql << 2;
    int n = blockIdx.x * WPB + wv;
    if (n >= N_NODES) return;
    float gL = gamma[lane], bL = beta[lane];
    float hval = h[(size_t)n * 64 + lane];  // coalesced stream
    float4 a4 = *(const float4*)&attn[f0];
    a4.x *= LOG2E;
    a4.y *= LOG2E;
    a4.z *= LOG2E;
    a4.w *= LOG2E;
    int beg = row_ptr[n], end = row_ptr[n + 1];
    int deg = end - beg;
    float4 fd4 = *(const float4*)&fd[(size_t)n * 64 + f0];
    float d = 0.f;
    float4 acc = make_float4(0.f, 0.f, 0.f, 0.f);
    for (int c0 = 0; c0 < deg; c0 += 64) {
        int cl = min(64, deg - c0);
        int sv = (lane < cl) ? srcs[beg + c0 + lane] : 0;
        int nt = (cl + 3) >> 2;
        ushort4 rowA = make_ushort4(0, 0, 0, 0), rowB = rowA;
        int sid0 = __shfl(sv, q, 64);
        if (q < cl) rowA = *(const ushort4*)&fs[(size_t)sid0 * 64 + f0];
        int sid1 = __shfl(sv, (4 + q) & 63, 64);
        if (4 + q < cl) rowB = *(const ushort4*)&fs[(size_t)sid1 * 64 + f0];
        for (int t = 0; t < nt; ++t) {
            int eoff = 4 * t + q;
            bool valid = eoff < cl;
            float4 cur = bf4_to_f4(rowA);
            rowA = rowB;
            int e2 = 4 * (t + 2) + q;
            int sid2 = __shfl(sv, e2 & 63, 64);
            if (e2 < cl) rowB = *(const ushort4*)&fs[(size_t)sid2 * 64 + f0];  // prefetch
            float vx = cur.x + fd4.x, vy = cur.y + fd4.y;
            float vz = cur.z + fd4.z, vw = cur.w + fd4.w;
            vx = fmaxf(vx, NEG_SLOPE * vx);
            vy = fmaxf(vy, NEG_SLOPE * vy);
            vz = fmaxf(vz, NEG_SLOPE * vz);
            vw = fmaxf(vw, NEG_SLOPE * vw);
            float sp = fmaf(a4.x, vx, fmaf(a4.y, vy, fmaf(a4.z, vz, a4.w * vw)));
            sp += __shfl_xor(sp, 1, 64);
            sp += __shfl_xor(sp, 2, 64);
            sp += __shfl_xor(sp, 4, 64);
            sp += __shfl_xor(sp, 8, 64);
            float w = valid ? fast_exp2(sp) : 0.f;  // no-max softmax: shift-invariant
            d += w;
            acc.x = fmaf(w, cur.x, acc.x);
            acc.y = fmaf(w, cur.y, acc.y);
            acc.z = fmaf(w, cur.z, acc.z);
            acc.w = fmaf(w, cur.w, acc.w);
        }
    }
    // merge the 4 per-quarter partial sums (pure additions)
    d += __shfl_xor(d, 16, 64);
    d += __shfl_xor(d, 32, 64);
    acc.x += __shfl_xor(acc.x, 16, 64);
    acc.y += __shfl_xor(acc.y, 16, 64);
    acc.z += __shfl_xor(acc.z, 16, 64);
    acc.w += __shfl_xor(acc.w, 16, 64);
    acc.x += __shfl_xor(acc.x, 32, 64);
    acc.y += __shfl_xor(acc.y, 32, 64);
    acc.z += __shfl_xor(acc.z, 32, 64);
    acc.w += __shfl_xor(acc.w, 32, 64);
    float inv = (d > 0.f) ? 1.f / d : 0.f;
    acc.x *= inv;
    acc.y *= inv;
    acc.z *= inv;
    acc.w *= inv;
    // transpose to lane=feature layout via LDS (same-wave, ordered)
    if (q == 0) *(float4*)&xpose[wv][f0] = acc;
    float val = xpose[wv][lane];
    // layernorm + exact gelu + residual, one feature per lane
    float mean = wave_sum64(val) * 0.015625f;
    float dev = val - mean;
    float var = wave_sum64(dev * dev) * 0.015625f;
    float rstd = rsqrtf(var + LN_EPS);
    float tval = fmaf(dev * rstd, gL, bL);
    float g = 0.5f * tval * (1.f + erff(tval * 0.70710678118654752f));
    h[(size_t)n * 64 + lane] = hval + g;
}

// ---------------- output projection [n,64] @ [64,8] + b (un-permute on store) ----------
__global__ void out_proj_kernel(const float* __restrict__ h, const int* __restrict__ perm,
                                const float* __restrict__ W, const float* __restrict__ b,
                                float* __restrict__ out) {
    __shared__ float Ws[64 * 8];
    __shared__ float bs[8];
    __shared__ float Hs[32][65];
    int t = threadIdx.x;
    for (int i = t; i < 512; i += 256) Ws[i] = W[i];
    if (t < 8) bs[t] = b[t];
    int n0 = blockIdx.x * 32;
    for (int i = t; i < 32 * 64; i += 256) {
        int r = i >> 6, c = i & 63;
        int n = n0 + r;
        Hs[r][c] = (n < N_NODES) ? h[(size_t)n * 64 + c] : 0.f;
    }
    __syncthreads();
    int nl = t >> 3, o = t & 7;
    int n = n0 + nl;
    if (n >= N_NODES) return;
    float acc = bs[o];
#pragma unroll
    for (int k = 0; k < 64; ++k) acc = fmaf(Hs[nl][k], Ws[k * 8 + o], acc);
    out[(size_t)perm[n] * 8 + o] = acc;  // un-permute (scattered 32B, one-time)
}

extern "C" void kernel_launch(void* const* d_in, const int* in_sizes, int n_in,
                              void* d_out, int out_size, void* d_ws, size_t ws_size,
                              hipStream_t stream) {
    const float* nodes = (const float*)d_in[0];
    const int* src = (const int*)d_in[1];
    const int* dst = (const int*)d_in[2];
    const float* w_in = (const float*)d_in[3];
    const float* b_in = (const float*)d_in[4];
    const float* w_src = (const float*)d_in[5];
    const float* b_src = (const float*)d_in[6];
    const float* w_dst = (const float*)d_in[7];
    const float* b_dst = (const float*)d_in[8];
    const float* attn = (const float*)d_in[9];
    const float* gamma = (const float*)d_in[10];
    const float* beta = (const float*)d_in[11];
    const float* w_out = (const float*)d_in[12];
    const float* b_out = (const float*)d_in[13];
    float* out = (float*)d_out;

    char* ws = (char*)d_ws;
    size_t off = 0;
    auto alloc = [&](size_t bytes) {
        void* p = ws + off;
        off += (bytes + 255) & ~(size_t)255;
        return p;
    };
    float* h = (float*)alloc((size_t)N_NODES * 64 * 4);
    unsigned short* fs = (unsigned short*)alloc((size_t)N_NODES * 64 * 2);
    float* fd = (float*)alloc((size_t)N_NODES * 64 * 4);
    unsigned short* wpk_hi = (unsigned short*)alloc((size_t)13 * 4096 * 2);
    unsigned short* wpk_lo = (unsigned short*)alloc((size_t)13 * 4096 * 2);
    int* deg = (int*)alloc((size_t)N_NODES * 4);
    int* row_ptr_p = (int*)alloc((size_t)(N_NODES + 1) * 4);
    int* pos_p = (int*)alloc((size_t)N_NODES * 4);
    int* srcs_p = (int*)alloc((size_t)N_EDGES * 4);
    int* bsum = (int*)alloc((size_t)NSCAN_BLOCKS * 4);
    int* hist = (int*)alloc((size_t)64 * 4);
    int* binpos = (int*)alloc((size_t)64 * 4);
    int* perm = (int*)alloc((size_t)N_NODES * 4);
    int* inv_perm = (int*)alloc((size_t)N_NODES * 4);

    // Permuted-space CSR: nodes relabeled by degree bucket (perm), edges translated.
    hipMemsetAsync(deg, 0, (size_t)N_NODES * 4, stream);
    count_deg<<<(N_EDGES + 255) / 256, 256, 0, stream>>>(dst, deg, hist);
    histo<<<NSCAN_BLOCKS, SCAN_B, 0, stream>>>(deg, hist);
    binscan<<<1, 64, 0, stream>>>(hist, binpos);
    bucket_nodes<<<NSCAN_BLOCKS, SCAN_B, 0, stream>>>(deg, binpos, perm, inv_perm);
    scan1p<<<NSCAN_BLOCKS, SCAN_B, 0, stream>>>(deg, perm, row_ptr_p, bsum);
    scan3p<<<NSCAN_BLOCKS, SCAN_B, 0, stream>>>(row_ptr_p, bsum, pos_p);
    scatter_edges<<<(N_EDGES + 255) / 256, 256, 0, stream>>>(dst, src, inv_perm, pos_p, srcs_p);

    // weight packing (bf16 hi/lo, MFMA fragment order)
    pack_w<<<13, 256, 0, stream>>>(w_in, w_src, w_dst, wpk_hi, wpk_lo);

    // input projection into permuted h (MFMA, split-bf16 = fp32 accuracy)
    mfma_in_proj<<<(N_NODES + 63) / 64, 256, 0, stream>>>(nodes, perm, wpk_hi, wpk_lo, b_in, h);

    for (int l = 0; l < NLAYERS; ++l) {
        mfma_dual<<<(N_NODES + 63) / 64, 256, 0, stream>>>(
            h, wpk_hi + (size_t)(1 + l) * 4096, wpk_lo + (size_t)(1 + l) * 4096,
            b_src + (size_t)l * 64, wpk_hi + (size_t)(7 + l) * 4096,
            wpk_lo + (size_t)(7 + l) * 4096, b_dst + (size_t)l * 64, fs, fd);
        node_fused_kernel<<<(N_NODES + WPB - 1) / WPB, 256, 0, stream>>>(
            fs, fd, row_ptr_p, srcs_p, attn + (size_t)l * 64, gamma + (size_t)l * 64,
            beta + (size_t)l * 64, h);
    }

    out_proj_kernel<<<(N_NODES + 31) / 32, 256, 0, stream>>>(h, perm, w_out, b_out, out);
}